// Round 4
// baseline (349.885 us; speedup 1.0000x reference)
//
#include <hip/hip_runtime.h>

// Problem constants
#define B_    4
#define L_    1024
#define D_    768
#define H_    12
#define NE_   42
#define M_    8
#define NE2_  (NE_ * NE_)   // 1764
#define MPAD_ 1792          // 1764 padded up to 14*128 for clean GEMM tiles

typedef unsigned short u16;
typedef unsigned int   u32;

__device__ __forceinline__ u16 f2bf(float f) {
    union { float f; u32 u; } c; c.f = f;
    u32 u = c.u;
    u32 r = (u + 0x7FFFu + ((u >> 16) & 1u)) >> 16;  // round-to-nearest-even
    return (u16)r;
}

// ---------------------------------------------------------------------------
// Kernel 0: zero the denominator accumulator D [B][NE2] f32 (ws is poisoned)
// ---------------------------------------------------------------------------
__global__ __launch_bounds__(256) void zero_d_kernel(float* __restrict__ D) {
    int i = blockIdx.x * 256 + threadIdx.x;
    if (i < B_ * NE2_) D[i] = 0.f;
}

// ---------------------------------------------------------------------------
// Kernel 1: ent_att[b,h,e,l] = (1/cnt) * sum_{valid m} attention[b,h,idx[b,e,m]+1,l]
// attention is f32 [B,H,L,L]. grid (H, NE, B), 128 threads;
// thread t covers l = t*8 .. t*8+7 (two float4 loads per mention row)
// ---------------------------------------------------------------------------
__global__ __launch_bounds__(128) void ent_att_kernel(
    const float* __restrict__ att, const int* __restrict__ midx,
    const int* __restrict__ mmask, float* __restrict__ ent) {
    const int h = blockIdx.x, e = blockIdx.y, b = blockIdx.z;
    const int t  = threadIdx.x;
    const int l0 = t * 8;
    const int mb = (b * NE_ + e) * M_;
    const size_t abase = ((size_t)(b * H_ + h)) * L_ * L_;

    float acc[8] = {0.f,0.f,0.f,0.f,0.f,0.f,0.f,0.f};
    int cnt = 0;
    for (int m = 0; m < M_; ++m) {
        int  im = midx[mb + m] + 1;                       // OFFSET = 1
        bool v  = (mmask[mb + m] > 0) && (im < L_);
        if (v) {
            ++cnt;
            const float* row = att + abase + (size_t)im * L_ + l0;
            float4 x0 = *(const float4*)(row);
            float4 x1 = *(const float4*)(row + 4);
            acc[0] += x0.x; acc[1] += x0.y; acc[2] += x0.z; acc[3] += x0.w;
            acc[4] += x1.x; acc[5] += x1.y; acc[6] += x1.z; acc[7] += x1.w;
        }
    }
    const float s = 1.0f / (float)(cnt < 1 ? 1 : cnt);
    float* o = ent + (((size_t)(b * H_ + h)) * NE_ + e) * L_ + l0;
    *(float4*)(o)     = make_float4(acc[0]*s, acc[1]*s, acc[2]*s, acc[3]*s);
    *(float4*)(o + 4) = make_float4(acc[4]*s, acc[5]*s, acc[6]*s, acc[7]*s);
}

// ---------------------------------------------------------------------------
// Kernel 2: transpose+convert sequence_output f32 [b][k=L][n=D] -> ST bf16
// [b][n=D][k=L]. grid (D/32, L/32, B), block (32,8)
// ---------------------------------------------------------------------------
__global__ __launch_bounds__(256) void transpose_kernel(
    const float* __restrict__ S, u16* __restrict__ T) {
    __shared__ u16 tile[32][33];
    const int b  = blockIdx.z;
    const int n0 = blockIdx.x * 32;
    const int k0 = blockIdx.y * 32;
    const int tx = threadIdx.x, ty = threadIdx.y;
    const float* Sb = S + (size_t)b * L_ * D_;
    u16*         Tb = T + (size_t)b * D_ * L_;
    #pragma unroll
    for (int i = 0; i < 4; ++i)
        tile[ty + i*8][tx] = f2bf(Sb[(size_t)(k0 + ty + i*8) * D_ + (n0 + tx)]);
    __syncthreads();
    #pragma unroll
    for (int i = 0; i < 4; ++i)
        Tb[(size_t)(n0 + ty + i*8) * L_ + (k0 + tx)] = tile[tx][ty + i*8];
}

// ---------------------------------------------------------------------------
// Kernel 3a: D[b][s*42+t] += sum_h sum_l e[b,h,s,l]*e[b,h,t,l]
// grid (lq=4, h=12, b=4), 256 threads. Stage 42 rows x 256 l in LDS (rows
// 42,43 zero-padded), compute 11x11 tiles of 4x4 register-blocked grams over
// two l-halves (242 work items), atomicAdd into D.
// ---------------------------------------------------------------------------
#define LQ_    256
#define PAD3A  260   // floats per row: 16B-aligned, rows offset by 4 banks

__global__ __launch_bounds__(256) void denom_kernel(
    const float* __restrict__ ent, float* __restrict__ D) {
    __shared__ float es[44 * PAD3A];
    const int lq = blockIdx.x, h = blockIdx.y, b = blockIdx.z;
    const int tid = threadIdx.x;
    const float* Eb = ent + ((size_t)(b * H_ + h) * NE_) * L_ + lq * LQ_;

    for (int i = tid; i < 44 * 64; i += 256) {
        int r = i >> 6, c = i & 63;
        float4 v = (r < NE_) ? *(const float4*)(Eb + (size_t)r * L_ + c * 4)
                             : make_float4(0.f, 0.f, 0.f, 0.f);
        *(float4*)&es[r * PAD3A + c * 4] = v;
    }
    __syncthreads();

    float* Db = D + b * NE2_;
    for (int item = tid; item < 242; item += 256) {
        const int tile = item >> 1, lh = item & 1;
        const int s0 = (tile / 11) * 4, t0 = (tile % 11) * 4;
        const float* ps = es + lh * 128;
        float a[4][4] = {};
        for (int l4 = 0; l4 < 32; ++l4) {
            float4 sv[4], tv[4];
            #pragma unroll
            for (int j = 0; j < 4; ++j) {
                sv[j] = *(const float4*)&ps[(s0 + j) * PAD3A + l4 * 4];
                tv[j] = *(const float4*)&ps[(t0 + j) * PAD3A + l4 * 4];
            }
            #pragma unroll
            for (int j = 0; j < 4; ++j)
                #pragma unroll
                for (int k = 0; k < 4; ++k)
                    a[j][k] += sv[j].x*tv[k].x + sv[j].y*tv[k].y
                             + sv[j].z*tv[k].z + sv[j].w*tv[k].w;
        }
        #pragma unroll
        for (int j = 0; j < 4; ++j)
            #pragma unroll
            for (int k = 0; k < 4; ++k) {
                int s = s0 + j, t = t0 + k;
                if (s < NE_ && t < NE_) atomicAdd(Db + s * NE_ + t, a[j][k]);
            }
    }
}

// ---------------------------------------------------------------------------
// Kernel 3b: W[b][s*42+t][l] = (sum_h e[h,s,l]*e[h,t,l]) / (D[b,s,t] + H*1e-5)
// (bf16). grid (lc=64, b=4), 256 threads. Stage e[12][42][16] f32 in LDS
// (read once), s-fragments register-cached as float4; each lane owns 4 l.
// Also zeroes pad rows 1764..1791.
// ---------------------------------------------------------------------------
__global__ __launch_bounds__(256) void wbuild_kernel(
    const float* __restrict__ ent, const float* __restrict__ D,
    u16* __restrict__ W) {
    __shared__ float eb[H_ * NE_ * 16];   // [h][e][16] contiguous, b128-aligned
    const int lc = blockIdx.x, b = blockIdx.y;
    const int tid = threadIdx.x;
    const float* Eb = ent + (size_t)b * H_ * NE_ * L_ + lc * 16;

    for (int i = tid; i < H_ * NE_ * 4; i += 256) {    // 2016 float4
        int he = i >> 2, c4 = i & 3;
        *(float4*)&eb[he * 16 + c4 * 4] = *(const float4*)(Eb + (size_t)he * L_ + c4 * 4);
    }
    __syncthreads();

    const int lane = tid & 63, w = tid >> 6;
    const int lg = lane & 3, tg = lane >> 2;
    const float* Db = D + b * NE2_;
    u16* Wb = W + ((size_t)b * MPAD_) * L_ + lc * 16 + lg * 4;

    for (int s = w; s < NE_; s += 4) {
        float4 es[H_];
        #pragma unroll
        for (int h = 0; h < H_; ++h)
            es[h] = *(const float4*)&eb[(h * NE_ + s) * 16 + lg * 4];
        for (int t = tg; t < NE_; t += 16) {
            const float dv = Db[s * NE_ + t];
            float4 a = {0.f, 0.f, 0.f, 0.f};
            #pragma unroll
            for (int h = 0; h < H_; ++h) {
                float4 e2 = *(const float4*)&eb[(h * NE_ + t) * 16 + lg * 4];
                a.x += es[h].x * e2.x; a.y += es[h].y * e2.y;
                a.z += es[h].z * e2.z; a.w += es[h].w * e2.w;
            }
            const float inv = 1.0f / (dv + (float)H_ * 1e-5f);
            ushort4 o;
            o.x = f2bf(a.x * inv); o.y = f2bf(a.y * inv);
            o.z = f2bf(a.z * inv); o.w = f2bf(a.w * inv);
            *(ushort4*)(Wb + (size_t)(s * NE_ + t) * L_) = o;
        }
    }
    // zero pad rows for the GEMM
    for (int i = tid; i < (MPAD_ - NE2_) * 16; i += 256) {
        int p = NE2_ + (i >> 4), l = i & 15;
        W[((size_t)b * MPAD_ + p) * L_ + lc * 16 + l] = 0;
    }
}

// ---------------------------------------------------------------------------
// Kernel 4: batched GEMM out[b] = W[b] (MPADx1024) @ S[b] (1024x768), bf16
// MFMA, f32 output. 128x128x32 tiles, 4 waves 2x2, global_load_lds staging.
// grid (MPAD/128=14, D/128=6, B)
// ---------------------------------------------------------------------------
typedef __attribute__((ext_vector_type(8))) __bf16 bf16x8;
typedef __attribute__((ext_vector_type(4))) float  f32x4;

__global__ __launch_bounds__(256) void gemm_kernel(
    const u16* __restrict__ W, const u16* __restrict__ T, float* __restrict__ out) {
    __shared__ __align__(16) u16 As[128 * 32];
    __shared__ __align__(16) u16 Bs[128 * 32];
    const int b = blockIdx.z;
    const u16* Ab = W + (size_t)b * MPAD_ * L_ + (size_t)blockIdx.x * 128 * L_;
    const u16* Bb = T + (size_t)b * D_   * L_ + (size_t)blockIdx.y * 128 * L_;
    const int tid  = threadIdx.x;
    const int wave = tid >> 6, lane = tid & 63;
    const int wm = (wave & 1) * 64, wn = (wave >> 1) * 64;
    const int rm = lane & 15, kq = (lane >> 4) * 8;

    f32x4 acc[4][4] = {};

    for (int k0 = 0; k0 < L_; k0 += 32) {
        __syncthreads();
        #pragma unroll
        for (int i = 0; i < 2; ++i) {
            int c = i * 256 + tid;            // 512 chunks of 16B = 8KB tile
            int row = c >> 2, ko = (c & 3) * 8;
            __builtin_amdgcn_global_load_lds(
                (const __attribute__((address_space(1))) void*)(Ab + (size_t)row * L_ + k0 + ko),
                (__attribute__((address_space(3))) void*)(&As[c * 8]), 16, 0, 0);
            __builtin_amdgcn_global_load_lds(
                (const __attribute__((address_space(1))) void*)(Bb + (size_t)row * L_ + k0 + ko),
                (__attribute__((address_space(3))) void*)(&Bs[c * 8]), 16, 0, 0);
        }
        __syncthreads();

        bf16x8 af[4], bfr[4];
        #pragma unroll
        for (int i = 0; i < 4; ++i)
            af[i]  = *(const bf16x8*)&As[(wm + i*16 + rm) * 32 + kq];
        #pragma unroll
        for (int j = 0; j < 4; ++j)
            bfr[j] = *(const bf16x8*)&Bs[(wn + j*16 + rm) * 32 + kq];
        #pragma unroll
        for (int i = 0; i < 4; ++i)
            #pragma unroll
            for (int j = 0; j < 4; ++j)
                acc[i][j] = __builtin_amdgcn_mfma_f32_16x16x32_bf16(
                                af[i], bfr[j], acc[i][j], 0, 0, 0);
    }

    // Epilogue: C/D layout col = lane&15, row = (lane>>4)*4 + reg; f32 output
    const int row0 = blockIdx.x * 128 + wm;
    const int col0 = blockIdx.y * 128 + wn;
    const int cl = lane & 15, rq = (lane >> 4) * 4;
    float* Ob = out + (size_t)b * NE2_ * D_;
    #pragma unroll
    for (int i = 0; i < 4; ++i) {
        #pragma unroll
        for (int j = 0; j < 4; ++j) {
            const int col = col0 + j*16 + cl;
            #pragma unroll
            for (int r = 0; r < 4; ++r) {
                const int row = row0 + i*16 + rq + r;
                if (row < NE2_)
                    Ob[(size_t)row * D_ + col] = acc[i][j][r];
            }
        }
    }
}

// ---------------------------------------------------------------------------
// Workspace layout (bytes):
//   ent : f32 [B][H][NE][L]   =  8,257,536
//   W   : bf16 [B][MPAD][L]   = 14,680,064
//   ST  : bf16 [B][D][L]      =  6,291,456
//   D   : f32 [B][NE2]        =     28,224
// ---------------------------------------------------------------------------
#define ENT_BYTES (8257536)
#define W_BYTES   (14680064)
#define ST_BYTES  (6291456)

extern "C" void kernel_launch(void* const* d_in, const int* in_sizes, int n_in,
                              void* d_out, int out_size, void* d_ws, size_t ws_size,
                              hipStream_t stream) {
    const float* seq   = (const float*)d_in[0];   // [B,L,D]  f32
    const float* att   = (const float*)d_in[1];   // [B,H,L,L] f32
    const int*   midx  = (const int*)d_in[2];     // [B,NE,M]
    const int*   mmask = (const int*)d_in[3];     // [B,NE,M]
    float* out = (float*)d_out;                   // [B,NE,NE,D] f32

    char* ws  = (char*)d_ws;
    float* ent = (float*)ws;
    u16*   W   = (u16*)(ws + ENT_BYTES);
    u16*   ST  = (u16*)(ws + ENT_BYTES + W_BYTES);
    float* Dd  = (float*)(ws + ENT_BYTES + W_BYTES + ST_BYTES);

    zero_d_kernel<<<(B_ * NE2_ + 255) / 256, 256, 0, stream>>>(Dd);
    ent_att_kernel<<<dim3(H_, NE_, B_), 128, 0, stream>>>(att, midx, mmask, ent);
    transpose_kernel<<<dim3(D_/32, L_/32, B_), dim3(32, 8), 0, stream>>>(seq, ST);
    denom_kernel<<<dim3(4, H_, B_), 256, 0, stream>>>(ent, Dd);
    wbuild_kernel<<<dim3(64, B_), 256, 0, stream>>>(ent, Dd, W);
    gemm_kernel<<<dim3(MPAD_/128, D_/128, B_), 256, 0, stream>>>(W, ST, out);
}

// Round 5
// 343.304 us; speedup vs baseline: 1.0192x; 1.0192x over previous
//
#include <hip/hip_runtime.h>

// Problem constants
#define B_    4
#define L_    1024
#define D_    768
#define H_    12
#define NE_   42
#define M_    8
#define NE2_  (NE_ * NE_)   // 1764
#define MPAD_ 1792          // 1764 padded up to 14*128 for clean GEMM tiles

typedef unsigned short u16;
typedef unsigned int   u32;

__device__ __forceinline__ u16 f2bf(float f) {
    union { float f; u32 u; } c; c.f = f;
    u32 u = c.u;
    u32 r = (u + 0x7FFFu + ((u >> 16) & 1u)) >> 16;  // round-to-nearest-even
    return (u16)r;
}

// ---------------------------------------------------------------------------
// Kernel 1: ent_att[b,h,e,l] = (1/cnt) * sum_{valid m} attention[b,h,idx[b,e,m]+1,l]
// attention f32 [B,H,L,L]. grid (H, NE, B), 128 threads; thread t covers
// l = t*8..t*8+7. Blocks (h==0,e==0) also zero the D accumulator for their b.
// ---------------------------------------------------------------------------
__global__ __launch_bounds__(128) void ent_att_kernel(
    const float* __restrict__ att, const int* __restrict__ midx,
    const int* __restrict__ mmask, float* __restrict__ ent,
    float* __restrict__ D) {
    const int h = blockIdx.x, e = blockIdx.y, b = blockIdx.z;
    const int t  = threadIdx.x;

    if (h == 0 && e == 0) {          // fold zero_d: one block per b
        for (int i = t; i < NE2_; i += 128) D[b * NE2_ + i] = 0.f;
    }

    const int l0 = t * 8;
    const int mb = (b * NE_ + e) * M_;
    const size_t abase = ((size_t)(b * H_ + h)) * L_ * L_;

    float acc[8] = {0.f,0.f,0.f,0.f,0.f,0.f,0.f,0.f};
    int cnt = 0;
    for (int m = 0; m < M_; ++m) {
        int  im = midx[mb + m] + 1;                       // OFFSET = 1
        bool v  = (mmask[mb + m] > 0) && (im < L_);
        if (v) {
            ++cnt;
            const float* row = att + abase + (size_t)im * L_ + l0;
            float4 x0 = *(const float4*)(row);
            float4 x1 = *(const float4*)(row + 4);
            acc[0] += x0.x; acc[1] += x0.y; acc[2] += x0.z; acc[3] += x0.w;
            acc[4] += x1.x; acc[5] += x1.y; acc[6] += x1.z; acc[7] += x1.w;
        }
    }
    const float s = 1.0f / (float)(cnt < 1 ? 1 : cnt);
    float* o = ent + (((size_t)(b * H_ + h)) * NE_ + e) * L_ + l0;
    *(float4*)(o)     = make_float4(acc[0]*s, acc[1]*s, acc[2]*s, acc[3]*s);
    *(float4*)(o + 4) = make_float4(acc[4]*s, acc[5]*s, acc[6]*s, acc[7]*s);
}

// ---------------------------------------------------------------------------
// Kernel 2: transpose+convert sequence_output f32 [b][k=L][n=D] -> ST bf16
// [b][n=D][k=L]. grid (D/32, L/32, B), block (32,8)
// ---------------------------------------------------------------------------
__global__ __launch_bounds__(256) void transpose_kernel(
    const float* __restrict__ S, u16* __restrict__ T) {
    __shared__ u16 tile[32][33];
    const int b  = blockIdx.z;
    const int n0 = blockIdx.x * 32;
    const int k0 = blockIdx.y * 32;
    const int tx = threadIdx.x, ty = threadIdx.y;
    const float* Sb = S + (size_t)b * L_ * D_;
    u16*         Tb = T + (size_t)b * D_ * L_;
    #pragma unroll
    for (int i = 0; i < 4; ++i)
        tile[ty + i*8][tx] = f2bf(Sb[(size_t)(k0 + ty + i*8) * D_ + (n0 + tx)]);
    __syncthreads();
    #pragma unroll
    for (int i = 0; i < 4; ++i)
        Tb[(size_t)(n0 + ty + i*8) * L_ + (k0 + tx)] = tile[tx][ty + i*8];
}

// ---------------------------------------------------------------------------
// Kernel 3a: D[b][s*42+t] += sum_h sum_l e[b,h,s,l]*e[b,h,t,l]
// grid (lq=4, h=12, b=4), 256 threads. Stage 42 rows x 256 l in LDS,
// 11x11 tiles of 4x4 register-blocked grams over two l-halves, atomicAdd.
// ---------------------------------------------------------------------------
#define LQ_    256
#define PAD3A  260   // floats per row: 16B-aligned, rows offset by 4 banks

__global__ __launch_bounds__(256) void denom_kernel(
    const float* __restrict__ ent, float* __restrict__ D) {
    __shared__ float es[44 * PAD3A];
    const int lq = blockIdx.x, h = blockIdx.y, b = blockIdx.z;
    const int tid = threadIdx.x;
    const float* Eb = ent + ((size_t)(b * H_ + h) * NE_) * L_ + lq * LQ_;

    for (int i = tid; i < 44 * 64; i += 256) {
        int r = i >> 6, c = i & 63;
        float4 v = (r < NE_) ? *(const float4*)(Eb + (size_t)r * L_ + c * 4)
                             : make_float4(0.f, 0.f, 0.f, 0.f);
        *(float4*)&es[r * PAD3A + c * 4] = v;
    }
    __syncthreads();

    float* Db = D + b * NE2_;
    for (int item = tid; item < 242; item += 256) {
        const int tile = item >> 1, lh = item & 1;
        const int s0 = (tile / 11) * 4, t0 = (tile % 11) * 4;
        const float* ps = es + lh * 128;
        float a[4][4] = {};
        for (int l4 = 0; l4 < 32; ++l4) {
            float4 sv[4], tv[4];
            #pragma unroll
            for (int j = 0; j < 4; ++j) {
                sv[j] = *(const float4*)&ps[(s0 + j) * PAD3A + l4 * 4];
                tv[j] = *(const float4*)&ps[(t0 + j) * PAD3A + l4 * 4];
            }
            #pragma unroll
            for (int j = 0; j < 4; ++j)
                #pragma unroll
                for (int k = 0; k < 4; ++k)
                    a[j][k] += sv[j].x*tv[k].x + sv[j].y*tv[k].y
                             + sv[j].z*tv[k].z + sv[j].w*tv[k].w;
        }
        #pragma unroll
        for (int j = 0; j < 4; ++j)
            #pragma unroll
            for (int k = 0; k < 4; ++k) {
                int s = s0 + j, t = t0 + k;
                if (s < NE_ && t < NE_) atomicAdd(Db + s * NE_ + t, a[j][k]);
            }
    }
}

// ---------------------------------------------------------------------------
// Kernel 3b: W[b][s*42+t][l] = (sum_h e[h,s,l]*e[h,t,l]) / (D[b,s,t] + H*1e-5)
// (bf16). grid (lc=64, b=4), 256 threads. Stage e[12][42][16] f32 in LDS,
// s-fragments register-cached; each lane owns 4 l. Zeroes pad rows too.
// ---------------------------------------------------------------------------
__global__ __launch_bounds__(256) void wbuild_kernel(
    const float* __restrict__ ent, const float* __restrict__ D,
    u16* __restrict__ W) {
    __shared__ float eb[H_ * NE_ * 16];   // [h][e][16] contiguous
    const int lc = blockIdx.x, b = blockIdx.y;
    const int tid = threadIdx.x;
    const float* Eb = ent + (size_t)b * H_ * NE_ * L_ + lc * 16;

    for (int i = tid; i < H_ * NE_ * 4; i += 256) {    // 2016 float4
        int he = i >> 2, c4 = i & 3;
        *(float4*)&eb[he * 16 + c4 * 4] = *(const float4*)(Eb + (size_t)he * L_ + c4 * 4);
    }
    __syncthreads();

    const int lane = tid & 63, w = tid >> 6;
    const int lg = lane & 3, tg = lane >> 2;
    const float* Db = D + b * NE2_;
    u16* Wb = W + ((size_t)b * MPAD_) * L_ + lc * 16 + lg * 4;

    for (int s = w; s < NE_; s += 4) {
        float4 es[H_];
        #pragma unroll
        for (int h = 0; h < H_; ++h)
            es[h] = *(const float4*)&eb[(h * NE_ + s) * 16 + lg * 4];
        for (int t = tg; t < NE_; t += 16) {
            const float dv = Db[s * NE_ + t];
            float4 a = {0.f, 0.f, 0.f, 0.f};
            #pragma unroll
            for (int h = 0; h < H_; ++h) {
                float4 e2 = *(const float4*)&eb[(h * NE_ + t) * 16 + lg * 4];
                a.x += es[h].x * e2.x; a.y += es[h].y * e2.y;
                a.z += es[h].z * e2.z; a.w += es[h].w * e2.w;
            }
            const float inv = 1.0f / (dv + (float)H_ * 1e-5f);
            ushort4 o;
            o.x = f2bf(a.x * inv); o.y = f2bf(a.y * inv);
            o.z = f2bf(a.z * inv); o.w = f2bf(a.w * inv);
            *(ushort4*)(Wb + (size_t)(s * NE_ + t) * L_) = o;
        }
    }
    // zero pad rows for the GEMM
    for (int i = tid; i < (MPAD_ - NE2_) * 16; i += 256) {
        int p = NE2_ + (i >> 4), l = i & 15;
        W[((size_t)b * MPAD_ + p) * L_ + lc * 16 + l] = 0;
    }
}

// ---------------------------------------------------------------------------
// Kernel 4: batched GEMM out[b] = W[b] (MPADx1024) @ S[b] (1024x768), bf16
// MFMA, f32 output. 128x64 tiles (672 blocks = 2.6/CU for occupancy; the
// 128x128 version at 336 blocks left CUs at ~1 resident block). 4 waves 2x2,
// each wave 64x32 = 4x2 of 16x16x32 MFMAs. global_load_lds staging.
// grid (MPAD/128=14, D/64=12, B)
// ---------------------------------------------------------------------------
typedef __attribute__((ext_vector_type(8))) __bf16 bf16x8;
typedef __attribute__((ext_vector_type(4))) float  f32x4;

__global__ __launch_bounds__(256) void gemm_kernel(
    const u16* __restrict__ W, const u16* __restrict__ T, float* __restrict__ out) {
    __shared__ __align__(16) u16 As[128 * 32];   // 8 KB
    __shared__ __align__(16) u16 Bs[64 * 32];    // 4 KB
    const int b = blockIdx.z;
    const u16* Ab = W + (size_t)b * MPAD_ * L_ + (size_t)blockIdx.x * 128 * L_;
    const u16* Bb = T + (size_t)b * D_   * L_ + (size_t)blockIdx.y * 64  * L_;
    const int tid  = threadIdx.x;
    const int wave = tid >> 6, lane = tid & 63;
    const int wm = (wave & 1) * 64, wn = (wave >> 1) * 32;
    const int rm = lane & 15, kq = (lane >> 4) * 8;

    f32x4 acc[4][2] = {};

    for (int k0 = 0; k0 < L_; k0 += 32) {
        __syncthreads();
        #pragma unroll
        for (int i = 0; i < 2; ++i) {           // A: 512 16B chunks
            int c = i * 256 + tid;
            int row = c >> 2, ko = (c & 3) * 8;
            __builtin_amdgcn_global_load_lds(
                (const __attribute__((address_space(1))) void*)(Ab + (size_t)row * L_ + k0 + ko),
                (__attribute__((address_space(3))) void*)(&As[c * 8]), 16, 0, 0);
        }
        {                                       // B: 256 16B chunks
            int c = tid;
            int row = c >> 2, ko = (c & 3) * 8;
            __builtin_amdgcn_global_load_lds(
                (const __attribute__((address_space(1))) void*)(Bb + (size_t)row * L_ + k0 + ko),
                (__attribute__((address_space(3))) void*)(&Bs[c * 8]), 16, 0, 0);
        }
        __syncthreads();

        bf16x8 af[4], bfr[2];
        #pragma unroll
        for (int i = 0; i < 4; ++i)
            af[i]  = *(const bf16x8*)&As[(wm + i*16 + rm) * 32 + kq];
        #pragma unroll
        for (int j = 0; j < 2; ++j)
            bfr[j] = *(const bf16x8*)&Bs[(wn + j*16 + rm) * 32 + kq];
        #pragma unroll
        for (int i = 0; i < 4; ++i)
            #pragma unroll
            for (int j = 0; j < 2; ++j)
                acc[i][j] = __builtin_amdgcn_mfma_f32_16x16x32_bf16(
                                af[i], bfr[j], acc[i][j], 0, 0, 0);
    }

    // Epilogue: C/D layout col = lane&15, row = (lane>>4)*4 + reg; f32 output
    const int row0 = blockIdx.x * 128 + wm;
    const int col0 = blockIdx.y * 64  + wn;
    const int cl = lane & 15, rq = (lane >> 4) * 4;
    float* Ob = out + (size_t)b * NE2_ * D_;
    #pragma unroll
    for (int i = 0; i < 4; ++i) {
        #pragma unroll
        for (int j = 0; j < 2; ++j) {
            const int col = col0 + j*16 + cl;
            #pragma unroll
            for (int r = 0; r < 4; ++r) {
                const int row = row0 + i*16 + rq + r;
                if (row < NE2_)
                    Ob[(size_t)row * D_ + col] = acc[i][j][r];
            }
        }
    }
}

// ---------------------------------------------------------------------------
// Workspace layout (bytes):
//   ent : f32 [B][H][NE][L]   =  8,257,536
//   W   : bf16 [B][MPAD][L]   = 14,680,064
//   ST  : bf16 [B][D][L]      =  6,291,456
//   D   : f32 [B][NE2]        =     28,224
// ---------------------------------------------------------------------------
#define ENT_BYTES (8257536)
#define W_BYTES   (14680064)
#define ST_BYTES  (6291456)

extern "C" void kernel_launch(void* const* d_in, const int* in_sizes, int n_in,
                              void* d_out, int out_size, void* d_ws, size_t ws_size,
                              hipStream_t stream) {
    const float* seq   = (const float*)d_in[0];   // [B,L,D]  f32
    const float* att   = (const float*)d_in[1];   // [B,H,L,L] f32
    const int*   midx  = (const int*)d_in[2];     // [B,NE,M]
    const int*   mmask = (const int*)d_in[3];     // [B,NE,M]
    float* out = (float*)d_out;                   // [B,NE,NE,D] f32

    char* ws  = (char*)d_ws;
    float* ent = (float*)ws;
    u16*   W   = (u16*)(ws + ENT_BYTES);
    u16*   ST  = (u16*)(ws + ENT_BYTES + W_BYTES);
    float* Dd  = (float*)(ws + ENT_BYTES + W_BYTES + ST_BYTES);

    ent_att_kernel<<<dim3(H_, NE_, B_), 128, 0, stream>>>(att, midx, mmask, ent, Dd);
    transpose_kernel<<<dim3(D_/32, L_/32, B_), dim3(32, 8), 0, stream>>>(seq, ST);
    denom_kernel<<<dim3(4, H_, B_), 256, 0, stream>>>(ent, Dd);
    wbuild_kernel<<<dim3(64, B_), 256, 0, stream>>>(ent, Dd, W);
    gemm_kernel<<<dim3(MPAD_/128, D_/64, B_), 256, 0, stream>>>(W, ST, out);
}

// Round 6
// 317.563 us; speedup vs baseline: 1.1018x; 1.0811x over previous
//
#include <hip/hip_runtime.h>

// Problem constants
#define B_    4
#define L_    1024
#define D_    768
#define H_    12
#define NE_   42
#define M_    8
#define NE2_  (NE_ * NE_)   // 1764
#define MPAD_ 1792          // 1764 padded up to 14*128 for clean GEMM tiles

typedef unsigned short u16;
typedef unsigned int   u32;

__device__ __forceinline__ u16 f2bf(float f) {
    union { float f; u32 u; } c; c.f = f;
    u32 u = c.u;
    u32 r = (u + 0x7FFFu + ((u >> 16) & 1u)) >> 16;  // round-to-nearest-even
    return (u16)r;
}

// ---------------------------------------------------------------------------
// Kernel 1 (fused): blocks 0..503 build ent_att, blocks 504..1271 transpose.
//  ent_att[b,h,e,l] = (1/cnt) * sum_{valid m} attention[b,h,idx[b,e,m]+1,l]
//  ST: sequence_output f32 [b][k=L][n=D] -> bf16 [b][n=D][k=L]
// grid (1272, 1, B), 256 threads.
// ---------------------------------------------------------------------------
__global__ __launch_bounds__(256) void entatt_transpose_kernel(
    const float* __restrict__ att, const int* __restrict__ midx,
    const int* __restrict__ mmask, const float* __restrict__ S,
    float* __restrict__ ent, u16* __restrict__ T) {
    __shared__ u16 tile[32][33];
    const int x = blockIdx.x, b = blockIdx.z;
    const int tid = threadIdx.x;

    if (x < H_ * NE_) {                    // ---- ent_att role ----
        const int h = x % H_, e = x / H_;
        const int l0 = tid * 4;
        const int mb = (b * NE_ + e) * M_;
        const size_t abase = ((size_t)(b * H_ + h)) * L_ * L_;

        float4 acc = {0.f, 0.f, 0.f, 0.f};
        int cnt = 0;
        for (int m = 0; m < M_; ++m) {
            int  im = midx[mb + m] + 1;                   // OFFSET = 1
            bool v  = (mmask[mb + m] > 0) && (im < L_);
            if (v) {
                ++cnt;
                float4 xv = *(const float4*)(att + abase + (size_t)im * L_ + l0);
                acc.x += xv.x; acc.y += xv.y; acc.z += xv.z; acc.w += xv.w;
            }
        }
        const float s = 1.0f / (float)(cnt < 1 ? 1 : cnt);
        float* o = ent + (((size_t)(b * H_ + h)) * NE_ + e) * L_ + l0;
        *(float4*)o = make_float4(acc.x*s, acc.y*s, acc.z*s, acc.w*s);
    } else {                               // ---- transpose role ----
        const int y  = x - H_ * NE_;
        const int n0 = (y % (D_/32)) * 32;
        const int k0 = (y / (D_/32)) * 32;
        const int tx = tid & 31, ty = tid >> 5;     // 32 x 8
        const float* Sb = S + (size_t)b * L_ * D_;
        u16*         Tb = T + (size_t)b * D_ * L_;
        #pragma unroll
        for (int i = 0; i < 4; ++i)
            tile[ty + i*8][tx] = f2bf(Sb[(size_t)(k0 + ty + i*8) * D_ + (n0 + tx)]);
        __syncthreads();
        #pragma unroll
        for (int i = 0; i < 4; ++i)
            Tb[(size_t)(n0 + ty + i*8) * L_ + (k0 + tx)] = tile[tx][ty + i*8];
    }
}

// ---------------------------------------------------------------------------
// Kernel 2: denom partials — NO atomics. Each block (lq,h,b) stages 42 rows
// x 256 l in LDS, computes 4x4 register-blocked gram tiles over two l-halves,
// stores to disjoint slots Dpart[b][s*42+t][(h*4+lq)*2+lh].
// grid (4, 12, 4), 256 threads.
// ---------------------------------------------------------------------------
#define LQ_    256
#define PAD3A  260   // floats per row: 16B-aligned, rows offset by 4 banks
#define NSLOT  96    // (h*4+lq)*2+lh

__global__ __launch_bounds__(256) void denom_kernel(
    const float* __restrict__ ent, float* __restrict__ Dpart) {
    __shared__ float es[44 * PAD3A];
    const int lq = blockIdx.x, h = blockIdx.y, b = blockIdx.z;
    const int tid = threadIdx.x;
    const float* Eb = ent + ((size_t)(b * H_ + h) * NE_) * L_ + lq * LQ_;

    for (int i = tid; i < 44 * 64; i += 256) {
        int r = i >> 6, c = i & 63;
        float4 v = (r < NE_) ? *(const float4*)(Eb + (size_t)r * L_ + c * 4)
                             : make_float4(0.f, 0.f, 0.f, 0.f);
        *(float4*)&es[r * PAD3A + c * 4] = v;
    }
    __syncthreads();

    float* Dp = Dpart + (size_t)b * NE2_ * NSLOT;
    for (int item = tid; item < 242; item += 256) {
        const int tile = item >> 1, lh = item & 1;
        const int s0 = (tile / 11) * 4, t0 = (tile % 11) * 4;
        const int slot = (h * 4 + lq) * 2 + lh;
        const float* ps = es + lh * 128;
        float a[4][4] = {};
        for (int l4 = 0; l4 < 32; ++l4) {
            float4 sv[4], tv[4];
            #pragma unroll
            for (int j = 0; j < 4; ++j) {
                sv[j] = *(const float4*)&ps[(s0 + j) * PAD3A + l4 * 4];
                tv[j] = *(const float4*)&ps[(t0 + j) * PAD3A + l4 * 4];
            }
            #pragma unroll
            for (int j = 0; j < 4; ++j)
                #pragma unroll
                for (int k = 0; k < 4; ++k)
                    a[j][k] += sv[j].x*tv[k].x + sv[j].y*tv[k].y
                             + sv[j].z*tv[k].z + sv[j].w*tv[k].w;
        }
        #pragma unroll
        for (int j = 0; j < 4; ++j)
            #pragma unroll
            for (int k = 0; k < 4; ++k) {
                int s = s0 + j, t = t0 + k;
                if (s < NE_ && t < NE_)
                    Dp[(size_t)(s * NE_ + t) * NSLOT + slot] = a[j][k];
            }
    }
}

// ---------------------------------------------------------------------------
// Kernel 2b: D[b][st] = sum over 96 slots of Dpart. grid (28), 256 threads;
// one thread per (b,st), 24 float4 contiguous reads.
// ---------------------------------------------------------------------------
__global__ __launch_bounds__(256) void reduce_d_kernel(
    const float* __restrict__ Dpart, float* __restrict__ D) {
    const int i = blockIdx.x * 256 + threadIdx.x;
    if (i >= B_ * NE2_) return;
    const float4* p = (const float4*)(Dpart + (size_t)i * NSLOT);
    float4 s4 = {0.f, 0.f, 0.f, 0.f};
    #pragma unroll
    for (int j = 0; j < NSLOT / 4; ++j) {
        float4 v = p[j];
        s4.x += v.x; s4.y += v.y; s4.z += v.z; s4.w += v.w;
    }
    D[i] = s4.x + s4.y + s4.z + s4.w;
}

// ---------------------------------------------------------------------------
// Kernel 3: W[b][s*42+t][l] = (sum_h e[h,s,l]*e[h,t,l]) / (D[b,s,t] + H*1e-5)
// (bf16). grid (lc=64, b=4), 256 threads. Stage e[12][42][16] f32 in LDS,
// s-fragments register-cached; each lane owns 4 l. Zeroes pad rows too.
// ---------------------------------------------------------------------------
__global__ __launch_bounds__(256) void wbuild_kernel(
    const float* __restrict__ ent, const float* __restrict__ D,
    u16* __restrict__ W) {
    __shared__ float eb[H_ * NE_ * 16];   // [h][e][16] contiguous
    const int lc = blockIdx.x, b = blockIdx.y;
    const int tid = threadIdx.x;
    const float* Eb = ent + (size_t)b * H_ * NE_ * L_ + lc * 16;

    for (int i = tid; i < H_ * NE_ * 4; i += 256) {    // 2016 float4
        int he = i >> 2, c4 = i & 3;
        *(float4*)&eb[he * 16 + c4 * 4] = *(const float4*)(Eb + (size_t)he * L_ + c4 * 4);
    }
    __syncthreads();

    const int lane = tid & 63, w = tid >> 6;
    const int lg = lane & 3, tg = lane >> 2;
    const float* Db = D + b * NE2_;
    u16* Wb = W + ((size_t)b * MPAD_) * L_ + lc * 16 + lg * 4;

    for (int s = w; s < NE_; s += 4) {
        float4 es[H_];
        #pragma unroll
        for (int h = 0; h < H_; ++h)
            es[h] = *(const float4*)&eb[(h * NE_ + s) * 16 + lg * 4];
        for (int t = tg; t < NE_; t += 16) {
            const float dv = Db[s * NE_ + t];
            float4 a = {0.f, 0.f, 0.f, 0.f};
            #pragma unroll
            for (int h = 0; h < H_; ++h) {
                float4 e2 = *(const float4*)&eb[(h * NE_ + t) * 16 + lg * 4];
                a.x += es[h].x * e2.x; a.y += es[h].y * e2.y;
                a.z += es[h].z * e2.z; a.w += es[h].w * e2.w;
            }
            const float inv = 1.0f / (dv + (float)H_ * 1e-5f);
            ushort4 o;
            o.x = f2bf(a.x * inv); o.y = f2bf(a.y * inv);
            o.z = f2bf(a.z * inv); o.w = f2bf(a.w * inv);
            *(ushort4*)(Wb + (size_t)(s * NE_ + t) * L_) = o;
        }
    }
    // zero pad rows for the GEMM
    for (int i = tid; i < (MPAD_ - NE2_) * 16; i += 256) {
        int p = NE2_ + (i >> 4), l = i & 15;
        W[((size_t)b * MPAD_ + p) * L_ + lc * 16 + l] = 0;
    }
}

// ---------------------------------------------------------------------------
// Kernel 4: batched GEMM out[b] = W[b] (MPADx1024) @ S[b] (1024x768), bf16
// MFMA, f32 output. 128x64 tiles, 672 blocks, 4 waves 2x2 (each 64x32 =
// 4x2 MFMAs). global_load_lds staging. grid (14, 12, B)
// ---------------------------------------------------------------------------
typedef __attribute__((ext_vector_type(8))) __bf16 bf16x8;
typedef __attribute__((ext_vector_type(4))) float  f32x4;

__global__ __launch_bounds__(256) void gemm_kernel(
    const u16* __restrict__ W, const u16* __restrict__ T, float* __restrict__ out) {
    __shared__ __align__(16) u16 As[128 * 32];   // 8 KB
    __shared__ __align__(16) u16 Bs[64 * 32];    // 4 KB
    const int b = blockIdx.z;
    const u16* Ab = W + (size_t)b * MPAD_ * L_ + (size_t)blockIdx.x * 128 * L_;
    const u16* Bb = T + (size_t)b * D_   * L_ + (size_t)blockIdx.y * 64  * L_;
    const int tid  = threadIdx.x;
    const int wave = tid >> 6, lane = tid & 63;
    const int wm = (wave & 1) * 64, wn = (wave >> 1) * 32;
    const int rm = lane & 15, kq = (lane >> 4) * 8;

    f32x4 acc[4][2] = {};

    for (int k0 = 0; k0 < L_; k0 += 32) {
        __syncthreads();
        #pragma unroll
        for (int i = 0; i < 2; ++i) {           // A: 512 16B chunks
            int c = i * 256 + tid;
            int row = c >> 2, ko = (c & 3) * 8;
            __builtin_amdgcn_global_load_lds(
                (const __attribute__((address_space(1))) void*)(Ab + (size_t)row * L_ + k0 + ko),
                (__attribute__((address_space(3))) void*)(&As[c * 8]), 16, 0, 0);
        }
        {                                       // B: 256 16B chunks
            int c = tid;
            int row = c >> 2, ko = (c & 3) * 8;
            __builtin_amdgcn_global_load_lds(
                (const __attribute__((address_space(1))) void*)(Bb + (size_t)row * L_ + k0 + ko),
                (__attribute__((address_space(3))) void*)(&Bs[c * 8]), 16, 0, 0);
        }
        __syncthreads();

        bf16x8 af[4], bfr[2];
        #pragma unroll
        for (int i = 0; i < 4; ++i)
            af[i]  = *(const bf16x8*)&As[(wm + i*16 + rm) * 32 + kq];
        #pragma unroll
        for (int j = 0; j < 2; ++j)
            bfr[j] = *(const bf16x8*)&Bs[(wn + j*16 + rm) * 32 + kq];
        #pragma unroll
        for (int i = 0; i < 4; ++i)
            #pragma unroll
            for (int j = 0; j < 2; ++j)
                acc[i][j] = __builtin_amdgcn_mfma_f32_16x16x32_bf16(
                                af[i], bfr[j], acc[i][j], 0, 0, 0);
    }

    // Epilogue: C/D layout col = lane&15, row = (lane>>4)*4 + reg; f32 output
    const int row0 = blockIdx.x * 128 + wm;
    const int col0 = blockIdx.y * 64  + wn;
    const int cl = lane & 15, rq = (lane >> 4) * 4;
    float* Ob = out + (size_t)b * NE2_ * D_;
    #pragma unroll
    for (int i = 0; i < 4; ++i) {
        #pragma unroll
        for (int j = 0; j < 2; ++j) {
            const int col = col0 + j*16 + cl;
            #pragma unroll
            for (int r = 0; r < 4; ++r) {
                const int row = row0 + i*16 + rq + r;
                if (row < NE2_)
                    Ob[(size_t)row * D_ + col] = acc[i][j][r];
            }
        }
    }
}

// ---------------------------------------------------------------------------
// Workspace layout (bytes):
//   ent   : f32 [B][H][NE][L]   =  8,257,536
//   W     : bf16 [B][MPAD][L]   = 14,680,064
//   ST    : bf16 [B][D][L]      =  6,291,456
//   D     : f32 [B][NE2]        =     28,224
//   Dpart : f32 [B][NE2][96]    =  2,709,504
// ---------------------------------------------------------------------------
#define ENT_BYTES (8257536)
#define W_BYTES   (14680064)
#define ST_BYTES  (6291456)
#define D_BYTES   (28224)

extern "C" void kernel_launch(void* const* d_in, const int* in_sizes, int n_in,
                              void* d_out, int out_size, void* d_ws, size_t ws_size,
                              hipStream_t stream) {
    const float* seq   = (const float*)d_in[0];   // [B,L,D]  f32
    const float* att   = (const float*)d_in[1];   // [B,H,L,L] f32
    const int*   midx  = (const int*)d_in[2];     // [B,NE,M]
    const int*   mmask = (const int*)d_in[3];     // [B,NE,M]
    float* out = (float*)d_out;                   // [B,NE,NE,D] f32

    char* ws  = (char*)d_ws;
    float* ent   = (float*)ws;
    u16*   W     = (u16*)(ws + ENT_BYTES);
    u16*   ST    = (u16*)(ws + ENT_BYTES + W_BYTES);
    float* Dd    = (float*)(ws + ENT_BYTES + W_BYTES + ST_BYTES);
    float* Dpart = (float*)(ws + ENT_BYTES + W_BYTES + ST_BYTES + D_BYTES);

    entatt_transpose_kernel<<<dim3(H_*NE_ + (D_/32)*(L_/32), 1, B_), 256, 0, stream>>>(
        att, midx, mmask, seq, ent, ST);
    denom_kernel<<<dim3(4, H_, B_), 256, 0, stream>>>(ent, Dpart);
    reduce_d_kernel<<<(B_ * NE2_ + 255) / 256, 256, 0, stream>>>(Dpart, Dd);
    wbuild_kernel<<<dim3(64, B_), 256, 0, stream>>>(ent, Dd, W);
    gemm_kernel<<<dim3(MPAD_/128, D_/64, B_), 256, 0, stream>>>(W, ST, out);
}